// Round 1
// baseline (270.173 us; speedup 1.0000x reference)
//
#include <hip/hip_runtime.h>

#define N 20000
#define E 200000
#define IN 128
#define OUT 128
#define NB 8
#define SI 16
#define SO 16
#define R 230
#define T 365

#define NPB 4   // destination nodes per block in the fused kernel

// CSR-by-destination scratch in module .bss (~1.04 MB). d_ws untouched; no
// runtime API calls in kernel_launch (graph-capture safe).
__device__ int g_cnt[N];     // in-degree histogram
__device__ int g_off[N];     // exclusive prefix (row offsets)
__device__ int g_cur[N];     // scatter cursors
__device__ int g_eid[E];     // edge ids grouped by destination

__global__ void zero_cnt_kernel() {
    int i = blockIdx.x * blockDim.x + threadIdx.x;
    if (i < N) g_cnt[i] = 0;
}

__global__ void hist_kernel(const int* __restrict__ edge_dst) {
    int e = blockIdx.x * blockDim.x + threadIdx.x;
    if (e < E) atomicAdd(&g_cnt[edge_dst[e]], 1);
}

// Single-block exclusive scan of g_cnt[N] -> g_off / g_cur.
__global__ __launch_bounds__(1024) void scan_kernel() {
    __shared__ int part[1024];
    const int tid = threadIdx.x;
    const int CH = (N + 1023) / 1024;     // 20
    const int base = tid * CH;
    int sum = 0;
    for (int j = 0; j < CH; ++j) {
        int idx = base + j;
        if (idx < N) sum += g_cnt[idx];
    }
    part[tid] = sum;
    __syncthreads();
    for (int d = 1; d < 1024; d <<= 1) {
        int v = 0;
        if (tid >= d) v = part[tid - d];
        __syncthreads();
        if (tid >= d) part[tid] += v;
        __syncthreads();
    }
    int run = (tid > 0) ? part[tid - 1] : 0;
    for (int j = 0; j < CH; ++j) {
        int idx = base + j;
        if (idx < N) {
            g_off[idx] = run;
            g_cur[idx] = run;
            run += g_cnt[idx];
        }
    }
}

__global__ void scatter_kernel(const int* __restrict__ edge_dst) {
    int e = blockIdx.x * blockDim.x + threadIdx.x;
    if (e < E) {
        int d = edge_dst[e];
        int pos = atomicAdd(&g_cur[d], 1);
        g_eid[pos] = e;
    }
}

// One block = NPB destination nodes, 128 threads (thread = output feature).
// Phase 1: self-loop h[n,:] @ loop_weight (h rows staged in LDS, broadcast).
// Phase 2: register-accumulated message aggregation over the node's CSR edges
//          (zero atomics). Phase 3: epilogue + time-embedding gather.
__global__ __launch_bounds__(128) void fused_kernel(
        const float* __restrict__ h,
        const float* __restrict__ edge_norm,
        const float* __restrict__ node_norm,
        const float* __restrict__ weight,
        const float* __restrict__ h_bias,
        const float* __restrict__ loop_weight,
        const float* __restrict__ time_embed,
        const int* __restrict__ edge_src,
        const int* __restrict__ edge_type,
        const int* __restrict__ time_idx,
        float* __restrict__ out) {
    __shared__ float hsm[IN * NPB];      // hsm[i*NPB + nl]
    const int tid  = threadIdx.x;        // output feature o
    const int base = blockIdx.x * NPB;

    for (int k = tid; k < NPB * IN; k += 128) {
        int nl = k >> 7;
        int i  = k & 127;
        hsm[i * NPB + nl] = h[(long)(base + nl) * IN + i];
    }
    __syncthreads();

    // ---- self-loop GEMM ----
    float acc[NPB];
#pragma unroll
    for (int nl = 0; nl < NPB; ++nl) acc[nl] = 0.f;

    for (int i = 0; i < IN; ++i) {
        float w = loop_weight[(long)i * OUT + tid];
        float4 hv = *reinterpret_cast<const float4*>(&hsm[i * NPB]); // broadcast
        acc[0] = fmaf(hv.x, w, acc[0]);
        acc[1] = fmaf(hv.y, w, acc[1]);
        acc[2] = fmaf(hv.z, w, acc[2]);
        acc[3] = fmaf(hv.w, w, acc[3]);
    }

    const int b  = tid >> 4;
    const int ol = tid & 15;
    const float bias = h_bias[tid];

    // ---- per-node edge aggregation (register accumulation, no atomics) ----
    for (int nl = 0; nl < NPB; ++nl) {
        const int n   = base + nl;
        const int st  = g_off[n];
        const int cnt = g_cnt[n];
        float agg = 0.f;
        if (cnt > 0) {
            int   s  = edge_src[g_eid[st]];
            int   r  = edge_type[g_eid[st]];
            float en = edge_norm[g_eid[st]];
            for (int k = 0; k < cnt; ++k) {
                // prefetch next edge's metadata (covers dependent-load latency)
                int s2 = 0, r2 = 0;
                float en2 = 0.f;
                if (k + 1 < cnt) {
                    int e2 = g_eid[st + k + 1];
                    s2  = edge_src[e2];
                    r2  = edge_type[e2];
                    en2 = edge_norm[e2];
                }
                const float4* hp =
                    reinterpret_cast<const float4*>(h + (long)s * IN + b * SI);
                const float* W =
                    weight + (long)r * (NB * SI * SO) + b * (SI * SO) + ol;
                float4 h0 = hp[0], h1 = hp[1], h2 = hp[2], h3 = hp[3];
                // two independent FMA chains for ILP
                float m0 = 0.f, m1 = 0.f;
                m0 = fmaf(h0.x, W[0 * SO],  m0);
                m0 = fmaf(h0.y, W[1 * SO],  m0);
                m0 = fmaf(h0.z, W[2 * SO],  m0);
                m0 = fmaf(h0.w, W[3 * SO],  m0);
                m1 = fmaf(h1.x, W[4 * SO],  m1);
                m1 = fmaf(h1.y, W[5 * SO],  m1);
                m1 = fmaf(h1.z, W[6 * SO],  m1);
                m1 = fmaf(h1.w, W[7 * SO],  m1);
                m0 = fmaf(h2.x, W[8 * SO],  m0);
                m0 = fmaf(h2.y, W[9 * SO],  m0);
                m0 = fmaf(h2.z, W[10 * SO], m0);
                m0 = fmaf(h2.w, W[11 * SO], m0);
                m1 = fmaf(h3.x, W[12 * SO], m1);
                m1 = fmaf(h3.y, W[13 * SO], m1);
                m1 = fmaf(h3.z, W[14 * SO], m1);
                m1 = fmaf(h3.w, W[15 * SO], m1);
                agg = fmaf(en, m0 + m1, agg);
                s = s2; r = r2; en = en2;
            }
        }
        float v = agg * node_norm[n] + bias + acc[nl];
        out[(long)n * OUT + tid] = fmaxf(v, 0.f);
        // Output 2: time_embed[time_idx[n]], f32 passthrough
        out[(long)N * OUT + (long)n * IN + tid] =
            time_embed[(long)time_idx[n] * IN + tid];
    }
}

extern "C" void kernel_launch(void* const* d_in, const int* in_sizes, int n_in,
                              void* d_out, int out_size, void* d_ws, size_t ws_size,
                              hipStream_t stream) {
    const float* h           = (const float*)d_in[0];
    const float* edge_norm   = (const float*)d_in[1];
    const float* node_norm   = (const float*)d_in[2];
    const float* weight      = (const float*)d_in[3];
    const float* h_bias      = (const float*)d_in[4];
    const float* loop_weight = (const float*)d_in[5];
    const float* time_embed  = (const float*)d_in[6];
    const int*   edge_src    = (const int*)d_in[7];
    const int*   edge_dst    = (const int*)d_in[8];
    const int*   edge_type   = (const int*)d_in[9];
    const int*   time_idx    = (const int*)d_in[10];
    float* out = (float*)d_out;

    zero_cnt_kernel<<<(N + 255) / 256, 256, 0, stream>>>();
    hist_kernel<<<(E + 255) / 256, 256, 0, stream>>>(edge_dst);
    scan_kernel<<<1, 1024, 0, stream>>>();
    scatter_kernel<<<(E + 255) / 256, 256, 0, stream>>>(edge_dst);
    fused_kernel<<<N / NPB, 128, 0, stream>>>(
        h, edge_norm, node_norm, weight, h_bias, loop_weight,
        time_embed, edge_src, edge_type, time_idx, out);
}